// Round 6
// baseline (304.180 us; speedup 1.0000x reference)
//
#include <hip/hip_runtime.h>

#define NEG_SLOPE 0.2f
#define EPSV 1e-16f
#define NHEADS 8
#define NCH 16
#define BKT_SHIFT 8        // 256 nodes per bucket
#define BKT_NODES 256
#define CAP 8192           // fixed bucket capacity (mean 4096, ~64 sigma slack)
#define BIN_EPB 4096       // edges per block in bin pass (16/thread)
#define MAX_BKT 512

// Setup: S1[h]/D1[h] attention scalars + zero the bucket cursors.
__global__ __launch_bounds__(512) void gat_setup_kernel(
        const float* __restrict__ W1, const float* __restrict__ as1,
        const float* __restrict__ ad1, float* __restrict__ S1,
        float* __restrict__ D1, int* __restrict__ bkt_cnt, int nbuckets) {
    int t = threadIdx.x;
    for (int i = t; i < nbuckets; i += 512) bkt_cnt[i] = 0;
    if (t < NHEADS) {
        float s = 0.f, d = 0.f;
        for (int c = 0; c < NCH; ++c) {
            float w = W1[t * NCH + c];
            s += w * as1[t * NCH + c];
            d += w * ad1[t * NCH + c];
        }
        S1[t] = s;
        D1[t] = d;
    }
}

// Bin pass, block-aggregated: LDS bucket histogram gives local ranks; one
// global atomic per (block, nonempty bucket) reserves a contiguous range at
// fixed offset b*CAP; clustered writes of packed (src<<8 | dst&255).
__global__ __launch_bounds__(256) void gat_bin_kernel(
        const int* __restrict__ ei, int E, int nbuckets,
        int* __restrict__ bkt_cnt, unsigned int* __restrict__ binned) {
    __shared__ int hist[MAX_BKT];
    __shared__ int gbase[MAX_BKT];
    int t = threadIdx.x;
    for (int i = t; i < nbuckets; i += 256) hist[i] = 0;
    __syncthreads();
    int base = blockIdx.x * BIN_EPB;
    int lr[BIN_EPB / 256];   // 16 local ranks
#pragma unroll
    for (int k = 0; k < BIN_EPB / 1024; ++k) {
        int idx = base + k * 1024 + t * 4;
        if (idx + 3 < E) {
            int4 d4 = *(const int4*)(ei + E + idx);
            lr[4 * k + 0] = atomicAdd(&hist[d4.x >> BKT_SHIFT], 1);
            lr[4 * k + 1] = atomicAdd(&hist[d4.y >> BKT_SHIFT], 1);
            lr[4 * k + 2] = atomicAdd(&hist[d4.z >> BKT_SHIFT], 1);
            lr[4 * k + 3] = atomicAdd(&hist[d4.w >> BKT_SHIFT], 1);
        } else {
            for (int u = 0; u < 4; ++u)
                if (idx + u < E)
                    lr[4 * k + u] = atomicAdd(&hist[ei[E + idx + u] >> BKT_SHIFT], 1);
        }
    }
    __syncthreads();
    for (int i = t; i < nbuckets; i += 256) {
        int c = hist[i];
        gbase[i] = c ? (i * CAP + atomicAdd(&bkt_cnt[i], c)) : 0;
    }
    __syncthreads();
#pragma unroll
    for (int k = 0; k < BIN_EPB / 1024; ++k) {
        int idx = base + k * 1024 + t * 4;
        if (idx + 3 < E) {
            int4 s4 = *(const int4*)(ei + idx);
            int4 d4 = *(const int4*)(ei + E + idx);
            binned[gbase[d4.x >> BKT_SHIFT] + lr[4 * k + 0]] =
                ((unsigned int)s4.x << BKT_SHIFT) | (unsigned int)(d4.x & (BKT_NODES - 1));
            binned[gbase[d4.y >> BKT_SHIFT] + lr[4 * k + 1]] =
                ((unsigned int)s4.y << BKT_SHIFT) | (unsigned int)(d4.y & (BKT_NODES - 1));
            binned[gbase[d4.z >> BKT_SHIFT] + lr[4 * k + 2]] =
                ((unsigned int)s4.z << BKT_SHIFT) | (unsigned int)(d4.z & (BKT_NODES - 1));
            binned[gbase[d4.w >> BKT_SHIFT] + lr[4 * k + 3]] =
                ((unsigned int)s4.w << BKT_SHIFT) | (unsigned int)(d4.w & (BKT_NODES - 1));
        } else {
            for (int u = 0; u < 4; ++u)
                if (idx + u < E) {
                    unsigned int s = (unsigned int)ei[idx + u];
                    int d = ei[E + idx + u];
                    binned[gbase[d >> BKT_SHIFT] + lr[4 * k + u]] =
                        (s << BKT_SHIFT) | (unsigned int)(d & (BKT_NODES - 1));
                }
        }
    }
}

// Layer 1 fused: one block per bucket; edge-parallel over the bucket's binned
// entries, accumulate per-(head,node) den/num in LDS (h-major layout: bank =
// node%32, ~2-way conflicts = free). Finalize per node: self-loop, softmax,
// elu(W1*z+b1) dot W2 -> h2.
__global__ __launch_bounds__(256) void gat_gather1_kernel(
        int N, const float* __restrict__ x,
        const unsigned int* __restrict__ binned, const int* __restrict__ bkt_cnt,
        const float* __restrict__ S1g, const float* __restrict__ D1g,
        const float* __restrict__ W1, const float* __restrict__ b1,
        const float* __restrict__ W2, float* __restrict__ h2out) {
    __shared__ float accD[NHEADS][BKT_NODES];
    __shared__ float accN[NHEADS][BKT_NODES];
    __shared__ float xloc[BKT_NODES];
    int b = blockIdx.x, t = threadIdx.x;
    int node = (b << BKT_SHIFT) + t;
    xloc[t] = (node < N) ? x[node] : 0.f;
    float* aD = &accD[0][0];
    float* aN = &accN[0][0];
    for (int i = t; i < NHEADS * BKT_NODES; i += 256) { aD[i] = 0.f; aN[i] = 0.f; }
    float S1[NHEADS], D1[NHEADS];
#pragma unroll
    for (int h = 0; h < NHEADS; ++h) { S1[h] = S1g[h]; D1[h] = D1g[h]; }
    __syncthreads();
    int nE = bkt_cnt[b]; if (nE > CAP) nE = CAP;
    const unsigned int* bb = binned + (size_t)b * CAP;
    for (int j0 = 0; j0 < nE; j0 += 1024) {
        int idx = j0 + t * 4;
        unsigned int v[4];
        bool ok[4];
        if (idx + 3 < nE) {
            uint4 q = *(const uint4*)(bb + idx);
            v[0] = q.x; v[1] = q.y; v[2] = q.z; v[3] = q.w;
            ok[0] = ok[1] = ok[2] = ok[3] = true;
        } else {
#pragma unroll
            for (int u = 0; u < 4; ++u) {
                ok[u] = (idx + u < nE);
                v[u] = ok[u] ? bb[idx + u] : 0u;
            }
        }
        float xs[4]; int loc[4];
#pragma unroll
        for (int u = 0; u < 4; ++u) {
            loc[u] = v[u] & (BKT_NODES - 1);
            xs[u] = ok[u] ? x[v[u] >> BKT_SHIFT] : 0.f;
        }
#pragma unroll
        for (int u = 0; u < 4; ++u) {
            if (!ok[u]) continue;
            float xd = xloc[loc[u]];
#pragma unroll
            for (int h = 0; h < NHEADS; ++h) {
                float e = xs[u] * S1[h] + xd * D1[h];
                e = e > 0.f ? e : NEG_SLOPE * e;
                float ex = __expf(e);
                atomicAdd(&accD[h][loc[u]], ex);
                atomicAdd(&accN[h][loc[u]], ex * xs[u]);
            }
        }
    }
    __syncthreads();
    if (node >= N) return;
    float xn = xloc[t];
    float acc = 0.f;
#pragma unroll
    for (int h = 0; h < NHEADS; ++h) {
        float e = xn * (S1[h] + D1[h]);        // self-loop
        e = e > 0.f ? e : NEG_SLOPE * e;
        float ex = __expf(e);
        float den = accD[h][t] + ex + EPSV;
        float num = accN[h][t] + ex * xn;
        float z = num / den;
#pragma unroll
        for (int c = 0; c < NCH; ++c) {
            int k = h * NCH + c;
            float vv = W1[k] * z + b1[k];
            vv = vv > 0.f ? vv : (__expf(vv) - 1.f);   // elu
            acc += vv * W2[k];
        }
    }
    h2out[node] = acc;
}

// Layer 2 fused: single head/channel, same bucket-parallel structure.
__global__ __launch_bounds__(256) void gat_gather2_kernel(
        int N, const float* __restrict__ h2,
        const unsigned int* __restrict__ binned, const int* __restrict__ bkt_cnt,
        const float* __restrict__ as2p, const float* __restrict__ ad2p,
        const float* __restrict__ b2, float* __restrict__ out) {
    __shared__ float den2[BKT_NODES];
    __shared__ float num2[BKT_NODES];
    __shared__ float hloc[BKT_NODES];
    int b = blockIdx.x, t = threadIdx.x;
    int node = (b << BKT_SHIFT) + t;
    hloc[t] = (node < N) ? h2[node] : 0.f;
    den2[t] = 0.f;
    num2[t] = 0.f;
    float a_s = as2p[0], a_d = ad2p[0];
    __syncthreads();
    int nE = bkt_cnt[b]; if (nE > CAP) nE = CAP;
    const unsigned int* bb = binned + (size_t)b * CAP;
    for (int j0 = 0; j0 < nE; j0 += 1024) {
        int idx = j0 + t * 4;
        unsigned int v[4];
        bool ok[4];
        if (idx + 3 < nE) {
            uint4 q = *(const uint4*)(bb + idx);
            v[0] = q.x; v[1] = q.y; v[2] = q.z; v[3] = q.w;
            ok[0] = ok[1] = ok[2] = ok[3] = true;
        } else {
#pragma unroll
            for (int u = 0; u < 4; ++u) {
                ok[u] = (idx + u < nE);
                v[u] = ok[u] ? bb[idx + u] : 0u;
            }
        }
#pragma unroll
        for (int u = 0; u < 4; ++u) {
            if (!ok[u]) continue;
            int loc = v[u] & (BKT_NODES - 1);
            float hs = h2[v[u] >> BKT_SHIFT];
            float e = hs * a_s + hloc[loc] * a_d;
            e = e > 0.f ? e : NEG_SLOPE * e;
            float ex = __expf(e);
            atomicAdd(&den2[loc], ex);
            atomicAdd(&num2[loc], ex * hs);
        }
    }
    __syncthreads();
    if (node >= N) return;
    float hn = hloc[t];
    float e = hn * (a_s + a_d);                // self-loop
    e = e > 0.f ? e : NEG_SLOPE * e;
    float ex = __expf(e);
    float den = den2[t] + ex + EPSV;
    float num = num2[t] + ex * hn;
    out[node] = num / den + b2[0];
}

extern "C" void kernel_launch(void* const* d_in, const int* in_sizes, int n_in,
                              void* d_out, int out_size, void* d_ws, size_t ws_size,
                              hipStream_t stream) {
    const float* x   = (const float*)d_in[0];
    const int*   ei  = (const int*)d_in[1];
    const float* W1  = (const float*)d_in[2];
    const float* as1 = (const float*)d_in[3];
    const float* ad1 = (const float*)d_in[4];
    const float* b1  = (const float*)d_in[5];
    const float* W2  = (const float*)d_in[6];
    const float* as2 = (const float*)d_in[7];
    const float* ad2 = (const float*)d_in[8];
    const float* b2  = (const float*)d_in[9];
    float* out = (float*)d_out;

    int N = in_sizes[0];       // 100000
    int E = in_sizes[1] / 2;   // 1600000

    int nbuckets = (N + BKT_NODES - 1) >> BKT_SHIFT;   // 391
    int nbin     = (E + BIN_EPB - 1) / BIN_EPB;        // 391

    // Workspace: S1[8]f | D1[8]f | h2[N]f | bkt_cnt[nbuckets]i |
    // binned[nbuckets*CAP + E]u  (~20 MB of the 268 MB ws)
    float* S1      = (float*)d_ws;
    float* D1      = S1 + 8;
    float* h2      = D1 + 8;
    int*   bkt_cnt = (int*)(h2 + N);
    unsigned int* binned = (unsigned int*)(bkt_cnt + nbuckets);

    gat_setup_kernel<<<1, 512, 0, stream>>>(W1, as1, ad1, S1, D1,
                                            bkt_cnt, nbuckets);
    gat_bin_kernel<<<nbin, 256, 0, stream>>>(ei, E, nbuckets, bkt_cnt, binned);
    gat_gather1_kernel<<<nbuckets, 256, 0, stream>>>(N, x, binned, bkt_cnt,
                                                     S1, D1, W1, b1, W2, h2);
    gat_gather2_kernel<<<nbuckets, 256, 0, stream>>>(N, h2, binned, bkt_cnt,
                                                     as2, ad2, b2, out);
}

// Round 7
// 135.459 us; speedup vs baseline: 2.2455x; 2.2455x over previous
//
#include <hip/hip_runtime.h>

#define NEG_SLOPE 0.2f
#define EPSV 1e-16f
#define NHEADS 8
#define NCH 16
#define BKT_SHIFT 8        // 256 nodes per bucket
#define BKT_NODES 256
#define CAP 8192           // fixed bucket capacity (mean 4096, ~64 sigma slack)
#define BIN_EPB 4096       // edges per block in bin pass (16/thread)
#define MAX_BKT 512

// Setup: S1[h]/D1[h] attention scalars + zero the bucket cursors.
__global__ __launch_bounds__(512) void gat_setup_kernel(
        const float* __restrict__ W1, const float* __restrict__ as1,
        const float* __restrict__ ad1, float* __restrict__ S1,
        float* __restrict__ D1, int* __restrict__ bkt_cnt, int nbuckets) {
    int t = threadIdx.x;
    for (int i = t; i < nbuckets; i += 512) bkt_cnt[i] = 0;
    if (t < NHEADS) {
        float s = 0.f, d = 0.f;
        for (int c = 0; c < NCH; ++c) {
            float w = W1[t * NCH + c];
            s += w * as1[t * NCH + c];
            d += w * ad1[t * NCH + c];
        }
        S1[t] = s;
        D1[t] = d;
    }
}

// Bin pass, block-aggregated: LDS bucket histogram gives local ranks; one
// global atomic per (block, nonempty bucket) reserves a contiguous range at
// fixed offset b*CAP; clustered writes of packed (src<<8 | dst&255).
__global__ __launch_bounds__(256) void gat_bin_kernel(
        const int* __restrict__ ei, int E, int nbuckets,
        int* __restrict__ bkt_cnt, unsigned int* __restrict__ binned) {
    __shared__ int hist[MAX_BKT];
    __shared__ int gbase[MAX_BKT];
    int t = threadIdx.x;
    for (int i = t; i < nbuckets; i += 256) hist[i] = 0;
    __syncthreads();
    int base = blockIdx.x * BIN_EPB;
    int lr[BIN_EPB / 256];   // 16 local ranks
#pragma unroll
    for (int k = 0; k < BIN_EPB / 1024; ++k) {
        int idx = base + k * 1024 + t * 4;
        if (idx + 3 < E) {
            int4 d4 = *(const int4*)(ei + E + idx);
            lr[4 * k + 0] = atomicAdd(&hist[d4.x >> BKT_SHIFT], 1);
            lr[4 * k + 1] = atomicAdd(&hist[d4.y >> BKT_SHIFT], 1);
            lr[4 * k + 2] = atomicAdd(&hist[d4.z >> BKT_SHIFT], 1);
            lr[4 * k + 3] = atomicAdd(&hist[d4.w >> BKT_SHIFT], 1);
        } else {
            for (int u = 0; u < 4; ++u)
                if (idx + u < E)
                    lr[4 * k + u] = atomicAdd(&hist[ei[E + idx + u] >> BKT_SHIFT], 1);
        }
    }
    __syncthreads();
    for (int i = t; i < nbuckets; i += 256) {
        int c = hist[i];
        gbase[i] = c ? (i * CAP + atomicAdd(&bkt_cnt[i], c)) : 0;
    }
    __syncthreads();
#pragma unroll
    for (int k = 0; k < BIN_EPB / 1024; ++k) {
        int idx = base + k * 1024 + t * 4;
        if (idx + 3 < E) {
            int4 s4 = *(const int4*)(ei + idx);
            int4 d4 = *(const int4*)(ei + E + idx);
            binned[gbase[d4.x >> BKT_SHIFT] + lr[4 * k + 0]] =
                ((unsigned int)s4.x << BKT_SHIFT) | (unsigned int)(d4.x & (BKT_NODES - 1));
            binned[gbase[d4.y >> BKT_SHIFT] + lr[4 * k + 1]] =
                ((unsigned int)s4.y << BKT_SHIFT) | (unsigned int)(d4.y & (BKT_NODES - 1));
            binned[gbase[d4.z >> BKT_SHIFT] + lr[4 * k + 2]] =
                ((unsigned int)s4.z << BKT_SHIFT) | (unsigned int)(d4.z & (BKT_NODES - 1));
            binned[gbase[d4.w >> BKT_SHIFT] + lr[4 * k + 3]] =
                ((unsigned int)s4.w << BKT_SHIFT) | (unsigned int)(d4.w & (BKT_NODES - 1));
        } else {
            for (int u = 0; u < 4; ++u)
                if (idx + u < E) {
                    unsigned int s = (unsigned int)ei[idx + u];
                    int d = ei[E + idx + u];
                    binned[gbase[d >> BKT_SHIFT] + lr[4 * k + u]] =
                        (s << BKT_SHIFT) | (unsigned int)(d & (BKT_NODES - 1));
                }
        }
    }
}

// Layer 1: per-bucket LDS counting sort, then per-node register gather
// (no atomics in the accumulate). Writes sorted src lists + row meta back
// to global for layer 2 reuse, and h2[n].
__global__ __launch_bounds__(256) void gat_gather1_kernel(
        int N, const float* __restrict__ x,
        unsigned int* __restrict__ binned, const int* __restrict__ bkt_cnt,
        const float* __restrict__ S1g, const float* __restrict__ D1g,
        const float* __restrict__ W1, const float* __restrict__ b1,
        const float* __restrict__ W2, float* __restrict__ h2out,
        int* __restrict__ row_start, int* __restrict__ row_deg) {
    __shared__ unsigned int ed[CAP];          // sorted src per local node
    __shared__ int cnt[BKT_NODES];            // per-local-node degree
    __shared__ int off[BKT_NODES];            // exclusive offsets (pristine)
    __shared__ int cur[BKT_NODES];            // scatter cursors
    __shared__ float xloc[BKT_NODES];
    int b = blockIdx.x, t = threadIdx.x;
    int node = (b << BKT_SHIFT) + t;
    xloc[t] = (node < N) ? x[node] : 0.f;
    cnt[t] = 0;
    __syncthreads();
    int nE = bkt_cnt[b]; if (nE > CAP) nE = CAP;
    const unsigned int* bb = binned + (size_t)b * CAP;
    // pass 1: count local dsts
    for (int j0 = 0; j0 < nE; j0 += 1024) {
        int idx = j0 + t * 4;
        if (idx + 3 < nE) {
            uint4 q = *(const uint4*)(bb + idx);
            atomicAdd(&cnt[q.x & (BKT_NODES - 1)], 1);
            atomicAdd(&cnt[q.y & (BKT_NODES - 1)], 1);
            atomicAdd(&cnt[q.z & (BKT_NODES - 1)], 1);
            atomicAdd(&cnt[q.w & (BKT_NODES - 1)], 1);
        } else {
            for (int u = 0; u < 4; ++u)
                if (idx + u < nE) atomicAdd(&cnt[bb[idx + u] & (BKT_NODES - 1)], 1);
        }
    }
    __syncthreads();
    // 256-wide Hillis-Steele scan -> exclusive offsets
    int c = cnt[t];
    off[t] = c;
    __syncthreads();
    for (int o = 1; o < 256; o <<= 1) {
        int v = (t >= o) ? off[t - o] : 0;
        __syncthreads();
        off[t] += v;
        __syncthreads();
    }
    int o_excl = off[t] - c;
    off[t] = o_excl;
    cur[t] = o_excl;
    __syncthreads();
    // pass 2: scatter src into sorted LDS positions
    for (int j0 = 0; j0 < nE; j0 += 1024) {
        int idx = j0 + t * 4;
        if (idx + 3 < nE) {
            uint4 q = *(const uint4*)(bb + idx);
            ed[atomicAdd(&cur[q.x & (BKT_NODES - 1)], 1)] = q.x >> BKT_SHIFT;
            ed[atomicAdd(&cur[q.y & (BKT_NODES - 1)], 1)] = q.y >> BKT_SHIFT;
            ed[atomicAdd(&cur[q.z & (BKT_NODES - 1)], 1)] = q.z >> BKT_SHIFT;
            ed[atomicAdd(&cur[q.w & (BKT_NODES - 1)], 1)] = q.w >> BKT_SHIFT;
        } else {
            for (int u = 0; u < 4; ++u)
                if (idx + u < nE) {
                    unsigned int v = bb[idx + u];
                    ed[atomicAdd(&cur[v & (BKT_NODES - 1)], 1)] = v >> BKT_SHIFT;
                }
        }
    }
    __syncthreads();
    // write back sorted srcs + row meta for layer 2 (coalesced)
    for (int j0 = 0; j0 < nE; j0 += 1024) {
        int idx = j0 + t * 4;
        if (idx + 3 < nE) {
            *(uint4*)(binned + (size_t)b * CAP + idx) = *(const uint4*)(ed + idx);
        } else {
            for (int u = 0; u < 4; ++u)
                if (idx + u < nE) binned[(size_t)b * CAP + idx + u] = ed[idx + u];
        }
    }
    if (node < N) {
        row_start[node] = b * CAP + o_excl;
        row_deg[node] = c;
    }
    // per-node register gather, unroll-by-4 for MLP on x[src] loads
    float S1[NHEADS], A[NHEADS], den[NHEADS], num[NHEADS];
    float xn = xloc[t];
#pragma unroll
    for (int h = 0; h < NHEADS; ++h) {
        S1[h] = S1g[h];
        A[h] = xn * D1g[h];
        float e = xn * S1[h] + A[h];          // self-loop
        e = e > 0.f ? e : NEG_SLOPE * e;
        float ex = __expf(e);
        den[h] = ex + EPSV;
        num[h] = ex * xn;
    }
    int j = 0;
    for (; j + 4 <= c; j += 4) {
        unsigned int e0 = ed[o_excl + j + 0], e1 = ed[o_excl + j + 1];
        unsigned int e2 = ed[o_excl + j + 2], e3 = ed[o_excl + j + 3];
        float x0 = x[e0], x1 = x[e1], x2 = x[e2], x3 = x[e3];
#pragma unroll
        for (int h = 0; h < NHEADS; ++h) {
            float ea = x0 * S1[h] + A[h]; ea = ea > 0.f ? ea : NEG_SLOPE * ea;
            float eb = x1 * S1[h] + A[h]; eb = eb > 0.f ? eb : NEG_SLOPE * eb;
            float ec = x2 * S1[h] + A[h]; ec = ec > 0.f ? ec : NEG_SLOPE * ec;
            float ee = x3 * S1[h] + A[h]; ee = ee > 0.f ? ee : NEG_SLOPE * ee;
            float fa = __expf(ea), fb = __expf(eb), fc = __expf(ec), fd = __expf(ee);
            den[h] += (fa + fb) + (fc + fd);
            num[h] += (fa * x0 + fb * x1) + (fc * x2 + fd * x3);
        }
    }
    for (; j < c; ++j) {
        unsigned int e0 = ed[o_excl + j];
        float x0 = x[e0];
#pragma unroll
        for (int h = 0; h < NHEADS; ++h) {
            float ea = x0 * S1[h] + A[h];
            ea = ea > 0.f ? ea : NEG_SLOPE * ea;
            float fa = __expf(ea);
            den[h] += fa;
            num[h] += fa * x0;
        }
    }
    if (node >= N) return;
    float acc = 0.f;
#pragma unroll
    for (int h = 0; h < NHEADS; ++h) {
        float z = num[h] / den[h];
#pragma unroll
        for (int cc = 0; cc < NCH; ++cc) {
            int k = h * NCH + cc;
            float vv = W1[k] * z + b1[k];
            vv = vv > 0.f ? vv : (__expf(vv) - 1.f);   // elu
            acc += vv * W2[k];
        }
    }
    h2out[node] = acc;
}

// Layer 2: node-parallel register gather over sorted runs.
__global__ __launch_bounds__(256) void gat_gather2_kernel(
        int N, const float* __restrict__ h2,
        const unsigned int* __restrict__ binned,
        const int* __restrict__ row_start, const int* __restrict__ row_deg,
        const float* __restrict__ as2p, const float* __restrict__ ad2p,
        const float* __restrict__ b2, float* __restrict__ out) {
    int n = blockIdx.x * blockDim.x + threadIdx.x;
    if (n >= N) return;
    float a_s = as2p[0], a_d = ad2p[0];
    float hn = h2[n];
    float ad = hn * a_d;
    float e = hn * a_s + ad;                  // self-loop
    e = e > 0.f ? e : NEG_SLOPE * e;
    float ex = __expf(e);
    float den = ex + EPSV;
    float num = ex * hn;
    int st = row_start[n], dg = row_deg[n];
    int j = 0;
    for (; j + 4 <= dg; j += 4) {
        unsigned int e0 = binned[st + j + 0], e1 = binned[st + j + 1];
        unsigned int e2 = binned[st + j + 2], e3 = binned[st + j + 3];
        float h0 = h2[e0], h1 = h2[e1], h3 = h2[e2], h4 = h2[e3];
        float ea = h0 * a_s + ad; ea = ea > 0.f ? ea : NEG_SLOPE * ea;
        float eb = h1 * a_s + ad; eb = eb > 0.f ? eb : NEG_SLOPE * eb;
        float ec = h3 * a_s + ad; ec = ec > 0.f ? ec : NEG_SLOPE * ec;
        float ee = h4 * a_s + ad; ee = ee > 0.f ? ee : NEG_SLOPE * ee;
        float fa = __expf(ea), fb = __expf(eb), fc = __expf(ec), fd = __expf(ee);
        den += (fa + fb) + (fc + fd);
        num += (fa * h0 + fb * h1) + (fc * h3 + fd * h4);
    }
    for (; j < dg; ++j) {
        unsigned int e0 = binned[st + j];
        float h0 = h2[e0];
        float ea = h0 * a_s + ad;
        ea = ea > 0.f ? ea : NEG_SLOPE * ea;
        float fa = __expf(ea);
        den += fa;
        num += fa * h0;
    }
    out[n] = num / den + b2[0];
}

extern "C" void kernel_launch(void* const* d_in, const int* in_sizes, int n_in,
                              void* d_out, int out_size, void* d_ws, size_t ws_size,
                              hipStream_t stream) {
    const float* x   = (const float*)d_in[0];
    const int*   ei  = (const int*)d_in[1];
    const float* W1  = (const float*)d_in[2];
    const float* as1 = (const float*)d_in[3];
    const float* ad1 = (const float*)d_in[4];
    const float* b1  = (const float*)d_in[5];
    const float* W2  = (const float*)d_in[6];
    const float* as2 = (const float*)d_in[7];
    const float* ad2 = (const float*)d_in[8];
    const float* b2  = (const float*)d_in[9];
    float* out = (float*)d_out;

    int N = in_sizes[0];       // 100000
    int E = in_sizes[1] / 2;   // 1600000

    int nbuckets = (N + BKT_NODES - 1) >> BKT_SHIFT;   // 391
    int nbin     = (E + BIN_EPB - 1) / BIN_EPB;        // 391
    int nb       = (N + 255) / 256;                    // 391

    // Workspace: S1[8]f | D1[8]f | h2[N]f | row_start[N]i | row_deg[N]i |
    // bkt_cnt[nbuckets]i | binned[nbuckets*CAP]u   (~14 MB of 268 MB ws)
    float* S1        = (float*)d_ws;
    float* D1        = S1 + 8;
    float* h2        = D1 + 8;
    int*   row_start = (int*)(h2 + N);
    int*   row_deg   = row_start + N;
    int*   bkt_cnt   = row_deg + N;
    unsigned int* binned = (unsigned int*)(bkt_cnt + nbuckets);

    gat_setup_kernel<<<1, 512, 0, stream>>>(W1, as1, ad1, S1, D1,
                                            bkt_cnt, nbuckets);
    gat_bin_kernel<<<nbin, 256, 0, stream>>>(ei, E, nbuckets, bkt_cnt, binned);
    gat_gather1_kernel<<<nbuckets, 256, 0, stream>>>(N, x, binned, bkt_cnt,
                                                     S1, D1, W1, b1, W2, h2,
                                                     row_start, row_deg);
    gat_gather2_kernel<<<nb, 256, 0, stream>>>(N, h2, binned, row_start, row_deg,
                                               as2, ad2, b2, out);
}